// Round 1
// baseline (322.015 us; speedup 1.0000x reference)
//
#include <hip/hip_runtime.h>

// Problem: L_p[b,d] = sum_e (sum_f Theta[d,f] * X[b,f,e])^2
// B=16384, F=50, E=64, D=128, fp32 in/out. bf16 MFMA compute (threshold 185.6 allows it).
//
// Orientation: C'[e][d] = X_b^T @ Theta^T via mfma_f32_16x16x32_bf16.
//   A-frag = X:    A[m=e(lane&15)][k=f(quad*8+j)]   (per-b, from global, guarded f<50)
//   B-frag = Theta: B[k=f(quad*8+j)][n=d(lane&15)]  (constant, preloaded, rows contiguous)
//   C/D:   col(lane&15)=d, row(quad*4+reg)=e  -> e lives in regs+quads => cheap squared-sum
// epilogue: s = sum_{et,reg} acc^2 ; shfl_xor 16,32 over quads ; coalesced 16-lane store.

#define NB 8
constexpr int kF = 50;
constexpr int kE = 64;
constexpr int kD = 128;
constexpr int kFE = kF * kE; // 3200

typedef __attribute__((ext_vector_type(8))) short short8;
typedef __attribute__((ext_vector_type(4))) float f32x4;

__device__ __forceinline__ short f2bf(float f) {
  // round-to-nearest-even fp32 -> bf16 (inputs are normal randoms; no NaN handling needed)
  unsigned u = __float_as_uint(f);
  u += 0x7FFFu + ((u >> 16) & 1u);
  return (short)(u >> 16);
}

__global__ __launch_bounds__(256, 3) void ip_kernel(
    const float* __restrict__ X, const float* __restrict__ Th,
    float* __restrict__ out) {
  const int tid  = threadIdx.x;
  const int wid  = tid >> 6;        // wave id 0..3, owns d in [32*wid, 32*wid+32)
  const int lane = tid & 63;
  const int q    = lane >> 4;       // quad 0..3
  const int m16  = lane & 15;

  // ---- Preload Theta B-frags (constant across all b) ----
  // th[dt][ks][j] = bf16(Theta[d][k]), d = 32*wid + 16*dt + m16, k = 32*ks + 8*q + j (0 if k>=50)
  short8 th[2][2];
  const int d0 = wid * 32;
#pragma unroll
  for (int dt = 0; dt < 2; ++dt) {
    const float* trow = Th + (size_t)(d0 + dt * 16 + m16) * kF;
#pragma unroll
    for (int ks = 0; ks < 2; ++ks) {
      short8 v;
#pragma unroll
      for (int j = 0; j < 8; ++j) {
        const int k = ks * 32 + q * 8 + j;
        const float f = (k < kF) ? trow[k] : 0.0f;
        v[j] = f2bf(f);
      }
      th[dt][ks] = v;
    }
  }

  const int b0 = blockIdx.x * NB;
  for (int ib = 0; ib < NB; ++ib) {
    const int b = b0 + ib;
    const float* xb = X + (size_t)b * kFE + m16; // lane-based column e = et*16 + m16

    f32x4 acc[4][2]; // [et][dt]
#pragma unroll
    for (int et = 0; et < 4; ++et)
#pragma unroll
      for (int dt = 0; dt < 2; ++dt)
        acc[et][dt] = (f32x4){0.f, 0.f, 0.f, 0.f};

    // Double-buffered per-et load groups (16 fp32 each): overlap load latency with cvt+MFMA.
    float xbuf[2][16];
#pragma unroll
    for (int i = 0; i < 16; ++i) {
      const int k = (i >> 3) * 32 + q * 8 + (i & 7);
      xbuf[0][i] = (k < kF) ? xb[k * kE] : 0.0f;
    }

#pragma unroll
    for (int et = 0; et < 4; ++et) {
      if (et < 3) {
#pragma unroll
        for (int i = 0; i < 16; ++i) {
          const int k = (i >> 3) * 32 + q * 8 + (i & 7);
          xbuf[(et + 1) & 1][i] = (k < kF) ? xb[k * kE + (et + 1) * 16] : 0.0f;
        }
      }
      short8 af[2];
#pragma unroll
      for (int ks = 0; ks < 2; ++ks) {
        short8 v;
#pragma unroll
        for (int j = 0; j < 8; ++j) v[j] = f2bf(xbuf[et & 1][ks * 8 + j]);
        af[ks] = v;
      }
#pragma unroll
      for (int dt = 0; dt < 2; ++dt) {
        acc[et][dt] = __builtin_amdgcn_mfma_f32_16x16x32_bf16(af[0], th[dt][0], acc[et][dt], 0, 0, 0);
        acc[et][dt] = __builtin_amdgcn_mfma_f32_16x16x32_bf16(af[1], th[dt][1], acc[et][dt], 0, 0, 0);
      }
    }

    // ---- Epilogue: L_p[b,d] = sum_e proj^2 ----
    float* orow = out + (size_t)b * kD + d0;
#pragma unroll
    for (int dt = 0; dt < 2; ++dt) {
      float s = 0.0f;
#pragma unroll
      for (int et = 0; et < 4; ++et)
#pragma unroll
        for (int r = 0; r < 4; ++r) {
          const float p = acc[et][dt][r];
          s = fmaf(p, p, s);
        }
      // each lane now has sum over e in {et*16 + q*4 + r}; fold the 4 quads
      s += __shfl_xor(s, 16, 64);
      s += __shfl_xor(s, 32, 64);
      if (lane < 16) orow[dt * 16 + lane] = s;
    }
  }
}

extern "C" void kernel_launch(void* const* d_in, const int* in_sizes, int n_in,
                              void* d_out, int out_size, void* d_ws, size_t ws_size,
                              hipStream_t stream) {
  const float* X  = (const float*)d_in[0];  // [16384, 50, 64] fp32
  const float* Th = (const float*)d_in[1];  // [128, 50] fp32
  float* out = (float*)d_out;               // [16384, 128] fp32
  ip_kernel<<<dim3(16384 / NB), dim3(256), 0, stream>>>(X, Th, out);
}

// Round 3
// 294.068 us; speedup vs baseline: 1.0950x; 1.0950x over previous
//
#include <hip/hip_runtime.h>

// L_p[b,d] = sum_e (sum_f Theta[d,f] * X[b,f,e])^2
// B=16384, F=50, E=64, D=128, fp32 in/out; bf16 MFMA compute.
//
// Per block: NB=8 batch rows. X_b staged global->LDS once (shared by all 4 waves),
// transposed to [e][f] bf16, row stride FS=72 shorts (16B-aligned b128 reads,
// bank-uniform). Double-buffered, 1 barrier per b.
// MFMA orientation (mfma_f32_16x16x32_bf16):
//   A[m=e(lane&15)][k=f(quad*8+j)]  <- ds_read_b128 from LDS
//   B[k=f][n=d(lane&15)]            <- Theta, preloaded in regs (wave owns 32 d's)
//   C/D: col(lane&15)=d, row(quad*4+reg)=e -> squared-sum = 32 fma + 2 shfl_xor.

#define NB 8
constexpr int kF  = 50;
constexpr int kE  = 64;
constexpr int kD  = 128;
constexpr int kFE = kF * kE;  // 3200
constexpr int FS  = 72;       // LDS row stride in shorts (bf16)

typedef __attribute__((ext_vector_type(8))) short short8;
typedef __attribute__((ext_vector_type(4))) short bf16x4;
typedef __attribute__((ext_vector_type(4))) float f32x4;

__device__ __forceinline__ short f2bf(float f) {
  // round-to-nearest-even fp32 -> bf16
  unsigned u = __float_as_uint(f);
  u += 0x7FFFu + ((u >> 16) & 1u);
  return (short)(u >> 16);
}

__global__ __launch_bounds__(256, 4) void ip_kernel(
    const float* __restrict__ X, const float* __restrict__ Th,
    float* __restrict__ out) {
  __shared__ __align__(16) short lds[2][kE * FS];  // 2 x 9216 shorts = 18432 B

  const int tid  = threadIdx.x;
  const int wid  = tid >> 6;   // wave id: owns d in [32*wid, 32*wid+32); staging f-quad group
  const int lane = tid & 63;
  const int q    = lane >> 4;  // quad
  const int m16  = lane & 15;
  const int se   = lane;       // staging e coordinate (0..63)

  // ---- zero tail f in [52,64) once (read by ks=1 A-frags, never re-written per-b) ----
  for (int i = tid; i < kE * 12 * 2; i += 256) {
    const int buf = (i >= kE * 12) ? 1 : 0;
    const int r = i - buf * kE * 12;
    lds[buf][(r / 12) * FS + 52 + (r % 12)] = 0;
  }

  // ---- Theta B-frags (constant): th[dt][ks][j] = Theta[d0+16dt+m16][32ks+8q+j], 0 if f>=50 ----
  short8 th[2][2];
  const int d0 = wid * 32;
#pragma unroll
  for (int dt = 0; dt < 2; ++dt) {
    const float* trow = Th + (size_t)(d0 + dt * 16 + m16) * kF;
#pragma unroll
    for (int ks = 0; ks < 2; ++ks) {
      short8 v;
#pragma unroll
      for (int j = 0; j < 8; ++j) {
        const int k = ks * 32 + q * 8 + j;
        v[j] = (k < kF) ? f2bf(trow[k]) : (short)0;
      }
      th[dt][ks] = v;
    }
  }

  // ---- staging: thread (se, jq=wid) loads 4 f's x 1 e per pass, coalesced along e ----
  auto stage = [&](int buf, int b) {
    const float* xb = X + (size_t)b * kFE + se;
    short* row = &lds[buf][se * FS];
#pragma unroll
    for (int p = 0; p < 3; ++p) {          // f = 16p + 4*wid + j  (all < 48)
      bf16x4 w;
#pragma unroll
      for (int j = 0; j < 4; ++j) w[j] = f2bf(xb[(16 * p + 4 * wid + j) * kE]);
      *reinterpret_cast<bf16x4*>(&row[16 * p + 4 * wid]) = w;
    }
    if (wid == 0) {                        // wave-uniform: f = 48,49 (+ zero 50,51)
      bf16x4 w;
      w[0] = f2bf(xb[48 * kE]);
      w[1] = f2bf(xb[49 * kE]);
      w[2] = 0; w[3] = 0;
      *reinterpret_cast<bf16x4*>(&row[48]) = w;
    }
  };

  const int b0 = blockIdx.x * NB;
  stage(0, b0);
  __syncthreads();

  for (int ib = 0; ib < NB; ++ib) {
    const int cur = ib & 1;
    const int b = b0 + ib;
    if (ib + 1 < NB) stage(cur ^ 1, b + 1);

    // ---- compute: 8 ds_read_b128 + 16 MFMA ----
    const short* L = &lds[cur][m16 * FS + q * 8];
    f32x4 acc[4][2];
#pragma unroll
    for (int et = 0; et < 4; ++et)
#pragma unroll
      for (int dt = 0; dt < 2; ++dt) acc[et][dt] = (f32x4){0.f, 0.f, 0.f, 0.f};

#pragma unroll
    for (int et = 0; et < 4; ++et) {
      const short8 a0 = *reinterpret_cast<const short8*>(&L[et * 16 * FS]);
      const short8 a1 = *reinterpret_cast<const short8*>(&L[et * 16 * FS + 32]);
#pragma unroll
      for (int dt = 0; dt < 2; ++dt) {
        acc[et][dt] = __builtin_amdgcn_mfma_f32_16x16x32_bf16(a0, th[dt][0], acc[et][dt], 0, 0, 0);
        acc[et][dt] = __builtin_amdgcn_mfma_f32_16x16x32_bf16(a1, th[dt][1], acc[et][dt], 0, 0, 0);
      }
    }

    // ---- epilogue: L_p[b,d] = sum_e proj^2 ----
    float sv[2];
#pragma unroll
    for (int dt = 0; dt < 2; ++dt) {
      float s = 0.0f;
#pragma unroll
      for (int et = 0; et < 4; ++et)
#pragma unroll
        for (int r = 0; r < 4; ++r) {
          const float p = acc[et][dt][r];
          s = fmaf(p, p, s);
        }
      s += __shfl_xor(s, 16, 64);
      s += __shfl_xor(s, 32, 64);
      sv[dt] = s;
    }
    if (lane < 32) out[(size_t)b * kD + d0 + lane] = (lane < 16) ? sv[0] : sv[1];

    __syncthreads();
  }
}

extern "C" void kernel_launch(void* const* d_in, const int* in_sizes, int n_in,
                              void* d_out, int out_size, void* d_ws, size_t ws_size,
                              hipStream_t stream) {
  const float* X  = (const float*)d_in[0];  // [16384, 50, 64] fp32
  const float* Th = (const float*)d_in[1];  // [128, 50] fp32
  float* out = (float*)d_out;               // [16384, 128] fp32
  ip_kernel<<<dim3(16384 / NB), dim3(256), 0, stream>>>(X, Th, out);
}

// Round 4
// 290.002 us; speedup vs baseline: 1.1104x; 1.0140x over previous
//
#include <hip/hip_runtime.h>

// L_p[b,d] = sum_e (sum_f Theta[d,f] * X[b,f,e])^2
// B=16384, F=50, E=64, D=128, fp32 in/out; bf16 MFMA compute.
//
// Per block: NB=8 batch rows. X_b staged global->LDS (transposed to [e][f] bf16,
// row stride FS=72 shorts: 16B-aligned b128 reads, bank-uniform 8/bank minimum).
// SOFTWARE PIPELINE (load->use distance = 1 iteration) to bury HBM latency:
//   iter ib: load_regs(b+2) [no wait] ; compute(b) ; cvt+ds_write(b+1) ; barrier
// MFMA orientation (mfma_f32_16x16x32_bf16):
//   A[m=e(lane&15)][k=f(quad*8+j)]  <- ds_read_b128 from LDS (shared by 4 waves)
//   B[k=f][n=d(lane&15)]            <- Theta, preloaded in regs (wave owns 32 d's)
//   C/D: col(lane&15)=d, row(quad*4+reg)=e -> squared-sum = 32 fma + 2 shfl_xor.

#define NB 8
constexpr int kF  = 50;
constexpr int kE  = 64;
constexpr int kD  = 128;
constexpr int kFE = kF * kE;  // 3200
constexpr int FS  = 72;       // LDS row stride in shorts (bf16)

typedef __attribute__((ext_vector_type(8))) short short8;
typedef __attribute__((ext_vector_type(4))) short bf16x4;
typedef __attribute__((ext_vector_type(4))) float f32x4;

__device__ __forceinline__ short f2bf(float f) {
  // round-to-nearest-even fp32 -> bf16
  unsigned u = __float_as_uint(f);
  u += 0x7FFFu + ((u >> 16) & 1u);
  return (short)(u >> 16);
}

__global__ __launch_bounds__(256, 4) void ip_kernel(
    const float* __restrict__ X, const float* __restrict__ Th,
    float* __restrict__ out) {
  __shared__ __align__(16) short lds[2][kE * FS];  // 2 x 9216 shorts = 18432 B

  const int tid  = threadIdx.x;
  const int wid  = tid >> 6;   // wave id: owns d in [32*wid,+32); staging f-group
  const int lane = tid & 63;
  const int q    = lane >> 4;  // quad
  const int m16  = lane & 15;
  const int se   = lane;       // staging e coordinate (0..63)

  // ---- zero tail f in [52,64) once (read by ks=1 A-frags, never re-written) ----
  for (int i = tid; i < kE * 12 * 2; i += 256) {
    const int buf = (i >= kE * 12) ? 1 : 0;
    const int r = i - buf * kE * 12;
    lds[buf][(r / 12) * FS + 52 + (r % 12)] = 0;
  }

  // ---- Theta B-frags: th[dt][ks][j] = Theta[d0+16dt+m16][32ks+8q+j], 0 if f>=50 ----
  short8 th[2][2];
  const int d0 = wid * 32;
#pragma unroll
  for (int dt = 0; dt < 2; ++dt) {
    const float* trow = Th + (size_t)(d0 + dt * 16 + m16) * kF;
#pragma unroll
    for (int ks = 0; ks < 2; ++ks) {
      short8 v;
#pragma unroll
      for (int j = 0; j < 8; ++j) {
        const int k = ks * 32 + q * 8 + j;
        v[j] = (k < kF) ? f2bf(trow[k]) : (short)0;
      }
      th[dt][ks] = v;
    }
  }

  const int b0 = blockIdx.x * NB;

  // Two in-flight register sets. Thread (se, wid) owns f = 16p+4*wid+j (p<3,j<4);
  // wave 0 additionally owns f = 48,49.
  float xr[2][14];

  auto load_regs = [&](int set, int b) {
    const float* xb = X + (size_t)b * kFE + se;
#pragma unroll
    for (int p = 0; p < 3; ++p)
#pragma unroll
      for (int j = 0; j < 4; ++j)
        xr[set][p * 4 + j] = xb[(16 * p + 4 * wid + j) * kE];
    if (wid == 0) {  // wave-uniform branch
      xr[set][12] = xb[48 * kE];
      xr[set][13] = xb[49 * kE];
    }
  };

  auto cvt_write = [&](int set, int buf) {
    short* row = &lds[buf][se * FS];
#pragma unroll
    for (int p = 0; p < 3; ++p) {
      bf16x4 w;
#pragma unroll
      for (int j = 0; j < 4; ++j) w[j] = f2bf(xr[set][p * 4 + j]);
      *reinterpret_cast<bf16x4*>(&row[16 * p + 4 * wid]) = w;
    }
    if (wid == 0) {  // f = 48,49 (+ zero 50,51)
      bf16x4 w;
      w[0] = f2bf(xr[set][12]);
      w[1] = f2bf(xr[set][13]);
      w[2] = 0; w[3] = 0;
      *reinterpret_cast<bf16x4*>(&row[48]) = w;
    }
  };

  // ---- prologue: fill buf0 with b0, issue loads for b0+1 ----
  load_regs(0, b0);
  cvt_write(0, 0);
  load_regs(1, b0 + 1);
  __syncthreads();

#pragma unroll
  for (int ib = 0; ib < NB; ++ib) {
    const int cur = ib & 1;
    const int b = b0 + ib;

    // issue loads for b+2 (consumed next iteration; overwrites set consumed last iter)
    if (ib + 2 < NB) load_regs(cur, b + 2);

    // ---- compute from lds[cur]: 8 ds_read_b128 + 16 MFMA ----
    const short* L = &lds[cur][m16 * FS + q * 8];
    f32x4 acc[4][2];
#pragma unroll
    for (int et = 0; et < 4; ++et)
#pragma unroll
      for (int dt = 0; dt < 2; ++dt) acc[et][dt] = (f32x4){0.f, 0.f, 0.f, 0.f};

#pragma unroll
    for (int et = 0; et < 4; ++et) {
      const short8 a0 = *reinterpret_cast<const short8*>(&L[et * 16 * FS]);
      const short8 a1 = *reinterpret_cast<const short8*>(&L[et * 16 * FS + 32]);
#pragma unroll
      for (int dt = 0; dt < 2; ++dt) {
        acc[et][dt] = __builtin_amdgcn_mfma_f32_16x16x32_bf16(a0, th[dt][0], acc[et][dt], 0, 0, 0);
        acc[et][dt] = __builtin_amdgcn_mfma_f32_16x16x32_bf16(a1, th[dt][1], acc[et][dt], 0, 0, 0);
      }
    }

    // ---- epilogue: L_p[b,d] = sum_e proj^2 ----
    float sv[2];
#pragma unroll
    for (int dt = 0; dt < 2; ++dt) {
      float s = 0.0f;
#pragma unroll
      for (int et = 0; et < 4; ++et)
#pragma unroll
        for (int r = 0; r < 4; ++r) {
          const float p = acc[et][dt][r];
          s = fmaf(p, p, s);
        }
      s += __shfl_xor(s, 16, 64);
      s += __shfl_xor(s, 32, 64);
      sv[dt] = s;
    }
    if (lane < 32) out[(size_t)b * kD + d0 + lane] = (lane < 16) ? sv[0] : sv[1];

    // ---- stage b+1 into the other buffer (loads issued one iteration ago) ----
    if (ib + 1 < NB) cvt_write(cur ^ 1, cur ^ 1);

    __syncthreads();
  }
}

extern "C" void kernel_launch(void* const* d_in, const int* in_sizes, int n_in,
                              void* d_out, int out_size, void* d_ws, size_t ws_size,
                              hipStream_t stream) {
  const float* X  = (const float*)d_in[0];  // [16384, 50, 64] fp32
  const float* Th = (const float*)d_in[1];  // [128, 50] fp32
  float* out = (float*)d_out;               // [16384, 128] fp32
  ip_kernel<<<dim3(16384 / NB), dim3(256), 0, stream>>>(X, Th, out);
}